// Round 2
// baseline (146.804 us; speedup 1.0000x reference)
//
#include <hip/hip_runtime.h>
#include <math.h>

namespace {

constexpr int BB = 8;
constexpr int NN = 1024;
constexpr int CC = 10;
constexpr float RADIUS = 0.04f;
constexpr float ACCEL_SCALE = 0.02f;
constexpr float MAX_VEL = 0.02f;
constexpr float MAX_POS = 1.0f;
constexpr float EPS = 1e-9f;
// prefilter threshold: R^2 = 0.0016; margin covers fma-contraction + EPS + ulps
constexpr float D2_PREFILTER = 0.0017f;

// grid = 1024 blocks (8 batches x 128 chunks), block = 256 threads.
// Each block: 8 i-rows; 32 subs per i-row; each sub sweeps 32 j's (stride 32).
__global__ __launch_bounds__(256, 4) void gnca_kernel(
    const float* __restrict__ x,   // (B, N, 10)
    const float* __restrict__ W1,  // (14, 16) row-major
    const float* __restrict__ b1,  // (16,)
    const float* __restrict__ W2,  // (16, 7) row-major
    const float* __restrict__ b2,  // (7,)
    float* __restrict__ out)       // (B, N, 10)
{
    __shared__ float4 nod_s[NN];      // {pos.x, pos.y, typ, pad} : 16 KB
    __shared__ float  W1b_s[240];     // W1 (224) then b1 (16)

    const int tid = threadIdx.x;
    const int blk = blockIdx.x;          // 0..1023
    const int b = blk >> 7;              // batch
    const int i_base = (blk & 127) * 8;  // 8 i-rows per block

    if (tid < 224) W1b_s[tid] = W1[tid];
    else if (tid < 240) W1b_s[tid] = b1[tid - 224];

    const float* __restrict__ xb = x + (size_t)b * NN * CC;

    for (int j = tid; j < NN; j += 256) {
        const float px = xb[j * CC + 0];
        const float py = xb[j * CC + 1];
        const float tp = xb[j * CC + 4];
        nod_s[j] = make_float4(px, py, tp, 0.0f);
    }
    __syncthreads();

    const int i_local = tid >> 5;   // 0..7
    const int sub     = tid & 31;   // 0..31
    const int i = i_base + i_local;

    const float4 ni = nod_s[i];
    const float pix = ni.x, piy = ni.y;

    float agg[16];
#pragma unroll
    for (int h = 0; h < 16; ++h) agg[h] = 0.0f;
    float deg = 0.0f;
    float cellnb = 0.0f;

#pragma unroll 4
    for (int jj = 0; jj < NN / 32; ++jj) {
        const int j = jj * 32 + sub;
        const float4 nj = nod_s[j];
        const float dx = nj.x - pix;   // rel = pos[j] - pos[i]
        const float dy = nj.y - piy;
        const float d2c = dx * dx + dy * dy;   // contraction fine (prefilter only)
        if (d2c < D2_PREFILTER) {
            // exact fp32 path, matches numpy boundary decisions bit-for-bit
            const float d2 = __fadd_rn(__fadd_rn(__fmul_rn(dx, dx), __fmul_rn(dy, dy)), EPS);
            const float dist = __fsqrt_rn(d2);
            if (dist < RADIUS && dist > 1e-6f) {
                const float tgt = nj.z;
                deg += 1.0f;
                cellnb += (tgt > 0.5f) ? 1.0f : 0.0f;
                const float* __restrict__ xj = xb + j * CC;
                float xv[10];
#pragma unroll
                for (int c = 0; c < 10; ++c) xv[c] = xj[c];
#pragma unroll
                for (int h = 0; h < 16; ++h) {
                    float v = W1b_s[224 + h];                 // b1
                    v += dist * W1b_s[h] + dx * W1b_s[16 + h]
                       + dy * W1b_s[32 + h] + tgt * W1b_s[48 + h];
#pragma unroll
                    for (int c = 0; c < 10; ++c) v += xv[c] * W1b_s[(4 + c) * 16 + h];
                    agg[h] += fmaxf(v, 0.0f);
                }
            }
        }
    }

    // reduce over 32 subs (aligned 32-lane groups; xor masks < 32 stay in-group)
#pragma unroll
    for (int m = 1; m < 32; m <<= 1) {
#pragma unroll
        for (int h = 0; h < 16; ++h) agg[h] += __shfl_xor(agg[h], m, 64);
        deg    += __shfl_xor(deg, m, 64);
        cellnb += __shfl_xor(cellnb, m, 64);
    }

    if (sub == 0) {
        const bool is_cell = ni.z > 0.5f;

        // only out[...,0:2] feeds back into the state
        float o0 = deg * b2[0];
        float o1 = deg * b2[1];
#pragma unroll
        for (int h = 0; h < 16; ++h) {
            o0 += agg[h] * W2[h * 7 + 0];
            o1 += agg[h] * W2[h * 7 + 1];
        }
        if (!is_cell) { o0 = 0.0f; o1 = 0.0f; }

        const float vx = xb[i * CC + 2];
        const float vy = xb[i * CC + 3];
        float nvx = vx, nvy = vy;
        float npx = pix, npy = piy;
        if (is_cell) {
            nvx = fminf(fmaxf(vx + o0 * ACCEL_SCALE, -MAX_VEL), MAX_VEL);
            nvy = fminf(fmaxf(vy + o1 * ACCEL_SCALE, -MAX_VEL), MAX_VEL);
            npx = fminf(fmaxf(pix + nvx, -MAX_POS), MAX_POS);
            npy = fminf(fmaxf(piy + nvy, -MAX_POS), MAX_POS);
        }

        const bool dead     = is_cell && (deg < 3.0f);
        const bool consumed = (!is_cell) && (cellnb >= 1.0f);
        const float keep = (dead || consumed) ? 0.0f : 1.0f;

        float* __restrict__ op = out + ((size_t)b * NN + i) * CC;
        op[0] = npx * keep;
        op[1] = npy * keep;
        op[2] = nvx * keep;
        op[3] = nvy * keep;
#pragma unroll
        for (int c = 4; c < 10; ++c) op[c] = xb[i * CC + c] * keep;
    }
}

}  // namespace

extern "C" void kernel_launch(void* const* d_in, const int* in_sizes, int n_in,
                              void* d_out, int out_size, void* d_ws, size_t ws_size,
                              hipStream_t stream) {
    const float* x  = (const float*)d_in[0];
    const float* W1 = (const float*)d_in[1];
    const float* b1 = (const float*)d_in[2];
    const float* W2 = (const float*)d_in[3];
    const float* b2 = (const float*)d_in[4];
    float* out = (float*)d_out;

    gnca_kernel<<<dim3(BB * 128), dim3(256), 0, stream>>>(x, W1, b1, W2, b2, out);
}

// Round 3
// 53.040 us; speedup vs baseline: 2.7678x; 2.7678x over previous
//
#include <hip/hip_runtime.h>
#include <math.h>

namespace {

constexpr int BB = 8;
constexpr int NN = 1024;
constexpr int CC = 10;
constexpr float RADIUS = 0.04f;
constexpr float ACCEL_SCALE = 0.02f;
constexpr float MAX_VEL = 0.02f;
constexpr float MAX_POS = 1.0f;
constexpr float EPS = 1e-9f;
// prefilter threshold: R^2 = 0.0016; margin covers fma-contraction + EPS + ulps
constexpr float D2_PREFILTER = 0.0017f;

// grid = 1024 blocks (8 batches x 128 chunks), block = 256 threads.
// Each block: 8 i-rows; 32 subs per i-row; each sub sweeps 32 j's (stride 32).
// NOTE: no min-waves hint in __launch_bounds__ — round 2 showed (256,4)
// caps VGPRs at 64 and spills agg[16] to scratch (172 MB of spill writes).
__global__ __launch_bounds__(256) void gnca_kernel(
    const float* __restrict__ x,   // (B, N, 10)
    const float* __restrict__ W1,  // (14, 16) row-major
    const float* __restrict__ b1,  // (16,)
    const float* __restrict__ W2,  // (16, 7) row-major
    const float* __restrict__ b2,  // (7,)
    float* __restrict__ out)       // (B, N, 10)
{
    __shared__ float4 nod_s[NN];      // {pos.x, pos.y, typ, pad} : 16 KB
    __shared__ float  W1b_s[240];     // W1 (224) then b1 (16)

    const int tid = threadIdx.x;
    const int blk = blockIdx.x;          // 0..1023
    const int b = blk >> 7;              // batch
    const int i_base = (blk & 127) * 8;  // 8 i-rows per block

    if (tid < 224) W1b_s[tid] = W1[tid];
    else if (tid < 240) W1b_s[tid] = b1[tid - 224];

    const float* __restrict__ xb = x + (size_t)b * NN * CC;

    for (int j = tid; j < NN; j += 256) {
        const float px = xb[j * CC + 0];
        const float py = xb[j * CC + 1];
        const float tp = xb[j * CC + 4];
        nod_s[j] = make_float4(px, py, tp, 0.0f);
    }
    __syncthreads();

    const int i_local = tid >> 5;   // 0..7
    const int sub     = tid & 31;   // 0..31
    const int i = i_base + i_local;

    const float4 ni = nod_s[i];
    const float pix = ni.x, piy = ni.y;

    float agg[16];
#pragma unroll
    for (int h = 0; h < 16; ++h) agg[h] = 0.0f;
    float deg = 0.0f;
    float cellnb = 0.0f;

    for (int jj = 0; jj < NN / 32; ++jj) {
        const int j = jj * 32 + sub;
        const float4 nj = nod_s[j];
        const float dx = nj.x - pix;   // rel = pos[j] - pos[i]
        const float dy = nj.y - piy;
        const float d2c = dx * dx + dy * dy;   // contraction fine (prefilter only)
        if (d2c < D2_PREFILTER) {
            // exact fp32 path, matches numpy boundary decisions bit-for-bit
            const float d2 = __fadd_rn(__fadd_rn(__fmul_rn(dx, dx), __fmul_rn(dy, dy)), EPS);
            const float dist = __fsqrt_rn(d2);
            if (dist < RADIUS && dist > 1e-6f) {
                const float tgt = nj.z;
                deg += 1.0f;
                cellnb += (tgt > 0.5f) ? 1.0f : 0.0f;
                const float* __restrict__ xj = xb + j * CC;
                float xv[10];
#pragma unroll
                for (int c = 0; c < 10; ++c) xv[c] = xj[c];
#pragma unroll
                for (int h = 0; h < 16; ++h) {
                    float v = W1b_s[224 + h];                 // b1
                    v += dist * W1b_s[h] + dx * W1b_s[16 + h]
                       + dy * W1b_s[32 + h] + tgt * W1b_s[48 + h];
#pragma unroll
                    for (int c = 0; c < 10; ++c) v += xv[c] * W1b_s[(4 + c) * 16 + h];
                    agg[h] += fmaxf(v, 0.0f);
                }
            }
        }
    }

    // reduce over 32 subs (aligned 32-lane groups; xor masks < 32 stay in-group)
#pragma unroll
    for (int m = 1; m < 32; m <<= 1) {
#pragma unroll
        for (int h = 0; h < 16; ++h) agg[h] += __shfl_xor(agg[h], m, 64);
        deg    += __shfl_xor(deg, m, 64);
        cellnb += __shfl_xor(cellnb, m, 64);
    }

    if (sub == 0) {
        const bool is_cell = ni.z > 0.5f;

        // only out[...,0:2] feeds back into the state
        float o0 = deg * b2[0];
        float o1 = deg * b2[1];
#pragma unroll
        for (int h = 0; h < 16; ++h) {
            o0 += agg[h] * W2[h * 7 + 0];
            o1 += agg[h] * W2[h * 7 + 1];
        }
        if (!is_cell) { o0 = 0.0f; o1 = 0.0f; }

        const float vx = xb[i * CC + 2];
        const float vy = xb[i * CC + 3];
        float nvx = vx, nvy = vy;
        float npx = pix, npy = piy;
        if (is_cell) {
            nvx = fminf(fmaxf(vx + o0 * ACCEL_SCALE, -MAX_VEL), MAX_VEL);
            nvy = fminf(fmaxf(vy + o1 * ACCEL_SCALE, -MAX_VEL), MAX_VEL);
            npx = fminf(fmaxf(pix + nvx, -MAX_POS), MAX_POS);
            npy = fminf(fmaxf(piy + nvy, -MAX_POS), MAX_POS);
        }

        const bool dead     = is_cell && (deg < 3.0f);
        const bool consumed = (!is_cell) && (cellnb >= 1.0f);
        const float keep = (dead || consumed) ? 0.0f : 1.0f;

        float* __restrict__ op = out + ((size_t)b * NN + i) * CC;
        op[0] = npx * keep;
        op[1] = npy * keep;
        op[2] = nvx * keep;
        op[3] = nvy * keep;
#pragma unroll
        for (int c = 4; c < 10; ++c) op[c] = xb[i * CC + c] * keep;
    }
}

}  // namespace

extern "C" void kernel_launch(void* const* d_in, const int* in_sizes, int n_in,
                              void* d_out, int out_size, void* d_ws, size_t ws_size,
                              hipStream_t stream) {
    const float* x  = (const float*)d_in[0];
    const float* W1 = (const float*)d_in[1];
    const float* b1 = (const float*)d_in[2];
    const float* W2 = (const float*)d_in[3];
    const float* b2 = (const float*)d_in[4];
    float* out = (float*)d_out;

    gnca_kernel<<<dim3(BB * 128), dim3(256), 0, stream>>>(x, W1, b1, W2, b2, out);
}

// Round 4
// 26.710 us; speedup vs baseline: 5.4963x; 1.9858x over previous
//
#include <hip/hip_runtime.h>
#include <math.h>

namespace {

constexpr int BB = 8;
constexpr int NN = 1024;
constexpr int CC = 10;
constexpr float RADIUS = 0.04f;
constexpr float ACCEL_SCALE = 0.02f;
constexpr float MAX_VEL = 0.02f;
constexpr float MAX_POS = 1.0f;
constexpr float EPS = 1e-9f;
// prefilter threshold: R^2 = 0.0016; margin covers fma-contraction + EPS + ulps
constexpr float D2_PREFILTER = 0.0017f;

// ---------------- kernel 1: per-node features ----------------
// feat[g][h] = b1[h] + sum_c x[g][c] * W1[(4+c)*16+h]    (g = b*N+j, 8192 nodes)
// nod[g]     = {pos.x, pos.y, typ, 0}
__global__ __launch_bounds__(256) void feat_kernel(
    const float* __restrict__ x, const float* __restrict__ W1,
    const float* __restrict__ b1, float* __restrict__ feat,
    float4* __restrict__ nod)
{
    __shared__ float W1x_s[160];
    __shared__ float b1_s[16];
    const int tid = threadIdx.x;
    if (tid < 160) W1x_s[tid] = W1[64 + tid];
    if (tid < 16)  b1_s[tid] = b1[tid];
    __syncthreads();

    const int g = blockIdx.x * 256 + tid;  // 0..8191
    const float* __restrict__ xr = x + (size_t)g * CC;
    float xv[10];
#pragma unroll
    for (int c = 0; c < 10; ++c) xv[c] = xr[c];
    nod[g] = make_float4(xv[0], xv[1], xv[4], 0.0f);

    float f[16];
#pragma unroll
    for (int h = 0; h < 16; ++h) {
        float a = b1_s[h];
#pragma unroll
        for (int c = 0; c < 10; ++c) a += xv[c] * W1x_s[c * 16 + h];
        f[h] = a;
    }
    float4* __restrict__ fo = (float4*)(feat + (size_t)g * 16);
    fo[0] = make_float4(f[0], f[1], f[2], f[3]);
    fo[1] = make_float4(f[4], f[5], f[6], f[7]);
    fo[2] = make_float4(f[8], f[9], f[10], f[11]);
    fo[3] = make_float4(f[12], f[13], f[14], f[15]);
}

// ---------------- kernel 2: pair sweep ----------------
// grid = 2048 blocks (8 batches x 256 chunks of 4 rows), block = 256 threads.
// 64 subs per i-row (one wave per row); each sub sweeps 16 j's (stride 64).
__global__ __launch_bounds__(256) void sweep_kernel(
    const float* __restrict__ x,   // (B, N, 10)
    const float* __restrict__ W1,  // (14, 16)
    const float* __restrict__ W2,  // (16, 7)
    const float* __restrict__ b2,  // (7,)
    const float* __restrict__ feat,
    const float4* __restrict__ nod,
    float* __restrict__ out)
{
    __shared__ float4 nod_s[NN];   // 16 KB
    __shared__ float  W1e_s[64];   // W1 rows 0..3
    __shared__ float  W2c_s[32];   // W2 cols 0 and 1

    const int tid = threadIdx.x;
    const int blk = blockIdx.x;          // 0..2047
    const int b = blk >> 8;              // batch
    const int i_base = (blk & 255) * 4;  // 4 i-rows per block

    if (tid < 64) W1e_s[tid] = W1[tid];
    else if (tid < 80)  W2c_s[tid - 64] = W2[(tid - 64) * 7 + 0];
    else if (tid < 96)  W2c_s[tid - 80 + 16] = W2[(tid - 80) * 7 + 1];

    const float4* __restrict__ nb = nod + (size_t)b * NN;
    for (int j = tid; j < NN; j += 256) nod_s[j] = nb[j];
    __syncthreads();

    const int i_local = tid >> 6;   // 0..3
    const int sub     = tid & 63;   // 0..63
    const int i = i_base + i_local;

    const float4 ni = nod_s[i];
    const float pix = ni.x, piy = ni.y;

    float agg[16];
#pragma unroll
    for (int h = 0; h < 16; ++h) agg[h] = 0.0f;
    float deg = 0.0f;
    float cellnb = 0.0f;

    for (int jj = 0; jj < NN / 64; ++jj) {
        const int j = jj * 64 + sub;
        const float4 nj = nod_s[j];
        const float dx = nj.x - pix;   // rel = pos[j] - pos[i]
        const float dy = nj.y - piy;
        const float d2c = dx * dx + dy * dy;   // contraction ok: prefilter only
        if (d2c < D2_PREFILTER) {
            // exact fp32 path, matches numpy boundary decisions bit-for-bit
            const float d2 = __fadd_rn(__fadd_rn(__fmul_rn(dx, dx), __fmul_rn(dy, dy)), EPS);
            const float dist = __fsqrt_rn(d2);
            if (dist < RADIUS && dist > 1e-6f) {
                const float tgt = nj.z;
                deg += 1.0f;
                cellnb += (tgt > 0.5f) ? 1.0f : 0.0f;
                const float4* __restrict__ fj =
                    (const float4*)(feat + ((size_t)b * NN + j) * 16);
                const float4 f0 = fj[0], f1 = fj[1], f2 = fj[2], f3 = fj[3];
                const float fv[16] = {f0.x, f0.y, f0.z, f0.w, f1.x, f1.y, f1.z, f1.w,
                                      f2.x, f2.y, f2.z, f2.w, f3.x, f3.y, f3.z, f3.w};
#pragma unroll
                for (int h = 0; h < 16; ++h) {
                    const float v = fv[h] + dist * W1e_s[h] + dx * W1e_s[16 + h]
                                  + dy * W1e_s[32 + h] + tgt * W1e_s[48 + h];
                    agg[h] += fmaxf(v, 0.0f);
                }
            }
        }
    }

    // fold agg into the two needed W2 columns BEFORE the cross-lane reduce
    float o0p = 0.0f, o1p = 0.0f;
#pragma unroll
    for (int h = 0; h < 16; ++h) {
        o0p += agg[h] * W2c_s[h];
        o1p += agg[h] * W2c_s[16 + h];
    }

#pragma unroll
    for (int m = 1; m < 64; m <<= 1) {
        o0p    += __shfl_xor(o0p, m, 64);
        o1p    += __shfl_xor(o1p, m, 64);
        deg    += __shfl_xor(deg, m, 64);
        cellnb += __shfl_xor(cellnb, m, 64);
    }

    if (sub == 0) {
        const bool is_cell = ni.z > 0.5f;
        const float* __restrict__ xb = x + (size_t)b * NN * CC;

        float o0 = deg * b2[0] + o0p;
        float o1 = deg * b2[1] + o1p;
        if (!is_cell) { o0 = 0.0f; o1 = 0.0f; }

        const float vx = xb[i * CC + 2];
        const float vy = xb[i * CC + 3];
        float nvx = vx, nvy = vy;
        float npx = pix, npy = piy;
        if (is_cell) {
            nvx = fminf(fmaxf(vx + o0 * ACCEL_SCALE, -MAX_VEL), MAX_VEL);
            nvy = fminf(fmaxf(vy + o1 * ACCEL_SCALE, -MAX_VEL), MAX_VEL);
            npx = fminf(fmaxf(pix + nvx, -MAX_POS), MAX_POS);
            npy = fminf(fmaxf(piy + nvy, -MAX_POS), MAX_POS);
        }

        const bool dead     = is_cell && (deg < 3.0f);
        const bool consumed = (!is_cell) && (cellnb >= 1.0f);
        const float keep = (dead || consumed) ? 0.0f : 1.0f;

        float* __restrict__ op = out + ((size_t)b * NN + i) * CC;
        op[0] = npx * keep;
        op[1] = npy * keep;
        op[2] = nvx * keep;
        op[3] = nvy * keep;
#pragma unroll
        for (int c = 4; c < 10; ++c) op[c] = xb[i * CC + c] * keep;
    }
}

// ---------------- fallback: round-3 single kernel (if ws too small) ----------------
__global__ __launch_bounds__(256) void gnca_fallback(
    const float* __restrict__ x, const float* __restrict__ W1,
    const float* __restrict__ b1, const float* __restrict__ W2,
    const float* __restrict__ b2, float* __restrict__ out)
{
    __shared__ float4 nod_s[NN];
    __shared__ float  W1b_s[240];

    const int tid = threadIdx.x;
    const int blk = blockIdx.x;
    const int b = blk >> 7;
    const int i_base = (blk & 127) * 8;

    if (tid < 224) W1b_s[tid] = W1[tid];
    else if (tid < 240) W1b_s[tid] = b1[tid - 224];

    const float* __restrict__ xb = x + (size_t)b * NN * CC;
    for (int j = tid; j < NN; j += 256) {
        nod_s[j] = make_float4(xb[j * CC + 0], xb[j * CC + 1], xb[j * CC + 4], 0.0f);
    }
    __syncthreads();

    const int i_local = tid >> 5;
    const int sub     = tid & 31;
    const int i = i_base + i_local;
    const float4 ni = nod_s[i];

    float agg[16];
#pragma unroll
    for (int h = 0; h < 16; ++h) agg[h] = 0.0f;
    float deg = 0.0f, cellnb = 0.0f;

    for (int jj = 0; jj < NN / 32; ++jj) {
        const int j = jj * 32 + sub;
        const float4 nj = nod_s[j];
        const float dx = nj.x - ni.x, dy = nj.y - ni.y;
        if (dx * dx + dy * dy < D2_PREFILTER) {
            const float d2 = __fadd_rn(__fadd_rn(__fmul_rn(dx, dx), __fmul_rn(dy, dy)), EPS);
            const float dist = __fsqrt_rn(d2);
            if (dist < RADIUS && dist > 1e-6f) {
                const float tgt = nj.z;
                deg += 1.0f;
                cellnb += (tgt > 0.5f) ? 1.0f : 0.0f;
                const float* __restrict__ xj = xb + j * CC;
                float xv[10];
#pragma unroll
                for (int c = 0; c < 10; ++c) xv[c] = xj[c];
#pragma unroll
                for (int h = 0; h < 16; ++h) {
                    float v = W1b_s[224 + h] + dist * W1b_s[h] + dx * W1b_s[16 + h]
                            + dy * W1b_s[32 + h] + tgt * W1b_s[48 + h];
#pragma unroll
                    for (int c = 0; c < 10; ++c) v += xv[c] * W1b_s[(4 + c) * 16 + h];
                    agg[h] += fmaxf(v, 0.0f);
                }
            }
        }
    }
#pragma unroll
    for (int m = 1; m < 32; m <<= 1) {
#pragma unroll
        for (int h = 0; h < 16; ++h) agg[h] += __shfl_xor(agg[h], m, 64);
        deg    += __shfl_xor(deg, m, 64);
        cellnb += __shfl_xor(cellnb, m, 64);
    }
    if (sub == 0) {
        const bool is_cell = ni.z > 0.5f;
        float o0 = deg * b2[0], o1 = deg * b2[1];
#pragma unroll
        for (int h = 0; h < 16; ++h) { o0 += agg[h] * W2[h * 7]; o1 += agg[h] * W2[h * 7 + 1]; }
        if (!is_cell) { o0 = 0.0f; o1 = 0.0f; }
        const float vx = xb[i * CC + 2], vy = xb[i * CC + 3];
        float nvx = vx, nvy = vy, npx = ni.x, npy = ni.y;
        if (is_cell) {
            nvx = fminf(fmaxf(vx + o0 * ACCEL_SCALE, -MAX_VEL), MAX_VEL);
            nvy = fminf(fmaxf(vy + o1 * ACCEL_SCALE, -MAX_VEL), MAX_VEL);
            npx = fminf(fmaxf(ni.x + nvx, -MAX_POS), MAX_POS);
            npy = fminf(fmaxf(ni.y + nvy, -MAX_POS), MAX_POS);
        }
        const bool dead = is_cell && (deg < 3.0f);
        const bool consumed = (!is_cell) && (cellnb >= 1.0f);
        const float keep = (dead || consumed) ? 0.0f : 1.0f;
        float* __restrict__ op = out + ((size_t)b * NN + i) * CC;
        op[0] = npx * keep; op[1] = npy * keep; op[2] = nvx * keep; op[3] = nvy * keep;
#pragma unroll
        for (int c = 4; c < 10; ++c) op[c] = xb[i * CC + c] * keep;
    }
}

}  // namespace

extern "C" void kernel_launch(void* const* d_in, const int* in_sizes, int n_in,
                              void* d_out, int out_size, void* d_ws, size_t ws_size,
                              hipStream_t stream) {
    const float* x  = (const float*)d_in[0];
    const float* W1 = (const float*)d_in[1];
    const float* b1 = (const float*)d_in[2];
    const float* W2 = (const float*)d_in[3];
    const float* b2 = (const float*)d_in[4];
    float* out = (float*)d_out;

    const size_t feat_bytes = (size_t)BB * NN * 16 * sizeof(float);   // 512 KB
    const size_t nod_bytes  = (size_t)BB * NN * sizeof(float4);       // 128 KB

    if (ws_size >= feat_bytes + nod_bytes) {
        float*  feat = (float*)d_ws;
        float4* nod  = (float4*)((char*)d_ws + feat_bytes);
        feat_kernel<<<dim3(BB * NN / 256), dim3(256), 0, stream>>>(x, W1, b1, feat, nod);
        sweep_kernel<<<dim3(BB * 256), dim3(256), 0, stream>>>(x, W1, W2, b2, feat, nod, out);
    } else {
        gnca_fallback<<<dim3(BB * 128), dim3(256), 0, stream>>>(x, W1, b1, W2, b2, out);
    }
}